// Round 6
// baseline (295.839 us; speedup 1.0000x reference)
//
#include <hip/hip_runtime.h>
#include <hip/hip_bf16.h>

// WSDAN fused pipeline, R13.
// Inputs (f32): fm [64][768][676], att_w [192][768] (rows 0..31 used),
//               att_b [192], fc_w [200][24576], fc_b [200]
// d_out (f32): p [64*200] | fm_n [64*32*768] | att_m [64*32*676]
//
// R13 = R12 with ONE change: the VGPR cap. R11/R12 used
// __launch_bounds__(512,4), which hipcc treated as 4 blocks/CU (8 waves/EU)
// -> 64 VGPRs -> ~60 regs/thread spilled to scratch (~56 MB fetch + ~64 MB
// write excess measured in R12; MfmaUtil 1.5%). This kernel needs ~120 live
// regs (accp 48 + AW 24 + pre 24 + addressing). Fix: pin exactly 4 waves/EU
// (= 2 blocks/CU, matching the LDS limit) via amdgpu_waves_per_eu(4,4)
// -> 128-VGPR budget, no spills.

typedef unsigned short u16;
typedef __bf16 bf16x8_t __attribute__((ext_vector_type(8)));
typedef float f32x4_t __attribute__((ext_vector_type(4)));
typedef unsigned int uint32x4 __attribute__((ext_vector_type(4)));

union Frag { uint32x4 u4; unsigned u[4]; u16 s[8]; bf16x8_t v; };
union BFU { __hip_bfloat16 h; u16 u; };

__device__ inline u16 f2b(float x) { BFU t; t.h = __float2bfloat16(x); return t.u; }

__device__ inline void load8_cvt(const float* p, Frag& f) {
    f32x4_t x0 = *(const f32x4_t*)(p);
    f32x4_t x1 = *(const f32x4_t*)(p + 4);
#pragma unroll
    for (int j = 0; j < 4; ++j) { f.s[j] = f2b(x0[j]); f.s[4 + j] = f2b(x1[j]); }
}

#define MFMA(a, b, c) __builtin_amdgcn_mfma_f32_16x16x32_bf16((a), (b), (c), 0, 0, 0)

// LDS (dynamic, 81,408 B; 2 x 81,408 <= 163,840 -> 2 blocks/CU):
//   T  : [768][40] u16, XOR-chunk swizzled (verified R10 formula):
//        off_u16(c,p) = c*40 + ((p>>3) ^ ((c>>3)&3))*8 + (p&7)
//   red: [8][32][17] f32   per-K-slice att partials
//   Sb : [32][40] u16      relu'd att tile (pool A operand), col = s*16+pp
#define TPITCH 40
#define REDP 17
#define RED_OFF 61440                           // 768*40*2
#define SB_OFF (RED_OFF + 8 * 32 * REDP * 4)    // 78848
#define LDS_BYTES (SB_OFF + 32 * TPITCH * 2)    // 81408

// ---- Pass 1 (fused): att + pooled partial (atomic) ----
// grid (8, 64), 512 threads (8 waves), 2 blocks/CU.
// 44 half-tiles of 16 cols split {6,6,6,6,6,6,4,4} across sp.
__global__ __launch_bounds__(512)
__attribute__((amdgpu_waves_per_eu(4, 4)))
void k_fused(
    const float* __restrict__ fm, const float* __restrict__ att_w,
    const float* __restrict__ att_b, float* __restrict__ att_out,
    float* __restrict__ pooled)
{
    const int sp = blockIdx.x;               // spatial eighth 0..7
    const int b  = blockIdx.y;
    const int t  = threadIdx.x;
    const int wv = t >> 6, l = t & 63, q = l >> 4, ln = l & 15;

    const int t0  = (sp < 6) ? sp * 3 : 18 + (sp - 6) * 2;  // full-tile base
    const int nh  = (sp < 6) ? 6 : 4;                       // half-tiles
    const int hg0 = t0 * 2;

    extern __shared__ char lds[];
    u16*   T   = (u16*)lds;
    float* red = (float*)(lds + RED_OFF);
    u16*   Sb  = (u16*)(lds + SB_OFF);

    // att_w A-fragments register-resident (kills the L2-evict HBM re-fetch)
    const int kwv = wv * 96;
    Frag AW[2][3];
#pragma unroll
    for (int mh = 0; mh < 2; ++mh)
#pragma unroll
        for (int ks = 0; ks < 3; ++ks)
            load8_cvt(att_w + (size_t)(mh * 16 + ln) * 768 + kwv + ks * 32 + q * 8,
                      AW[mh][ks]);

    const float bias = att_b[t >> 4];        // m owned in the reduce phase

    f32x4_t accp[2][6];                      // pooled acc: [mh][ct]
#pragma unroll
    for (int i = 0; i < 2; ++i)
#pragma unroll
        for (int j = 0; j < 6; ++j) accp[i][j] = f32x4_t{0.f, 0.f, 0.f, 0.f};

    // staging: thread covers c-rows rr+256i (i<3), 8 p-cols at (t&1)*8
    const int rr  = t >> 1;                  // 0..255
    const int ph8 = (t & 1) << 3;            // 0 or 8
    const int cw  = (rr >> 3) & 3;           // (c>>3)&3, i-invariant (256%32==0)
    const float* fb = fm + ((size_t)b * 768 + rr) * 676;
    f32x4_t pre[3][2];                       // 24 VGPR held across compute

    auto loadf = [&](int hg) {               // issue 6 f32x4 loads (in flight)
        const int c0 = hg * 16 + ph8;
        const bool ok0 = (c0 + 3) < 676;     // edge half-tiles 42/43 only
        const bool ok1 = (c0 + 7) < 676;
#pragma unroll
        for (int i = 0; i < 3; ++i) {
            const float* src = fb + (size_t)(i * 256) * 676 + c0;
            pre[i][0] = ok0 ? *(const f32x4_t*)(src)     : f32x4_t{0.f,0.f,0.f,0.f};
            pre[i][1] = ok1 ? *(const f32x4_t*)(src + 4) : f32x4_t{0.f,0.f,0.f,0.f};
        }
    };
    auto commit = [&](int s) {               // cvt + LDS write (waits vmcnt)
        const int chunk = (2 * s + (t & 1)) ^ cw;
#pragma unroll
        for (int i = 0; i < 3; ++i) {
            Frag w;
#pragma unroll
            for (int j = 0; j < 4; ++j) {
                w.s[j]     = f2b(pre[i][0][j]);
                w.s[4 + j] = f2b(pre[i][1][j]);
            }
            *(uint32x4*)(T + (rr + i * 256) * TPITCH + chunk * 8) = w.u4;
        }
    };

    loadf(hg0); commit(0); __syncthreads();

    for (int h = 0; h < nh; ++h) {
        const int hg = hg0 + h, s = h & 1;

        if (h + 1 < nh) loadf(hg + 1);       // issue early; awaited in commit

        // --- att: S_wv[32m][16p] over K-slice kwv..kwv+96, slot s ---
        // B elem (c = kwv+ks*32+q*8+j, p = s*16+ln): (c>>3)&3 == q here,
        // stored chunk = (2s + (ln>>3)) ^ q.
        {
            f32x4_t sa[2];
            sa[0] = f32x4_t{0.f,0.f,0.f,0.f};
            sa[1] = f32x4_t{0.f,0.f,0.f,0.f};
#pragma unroll
            for (int ks = 0; ks < 3; ++ks) {
                Frag bfr;
                const u16* bp = T + (kwv + ks * 32 + q * 8) * TPITCH
                              + (((2 * s + (ln >> 3)) ^ q) << 3) + (ln & 7);
#pragma unroll
                for (int j = 0; j < 8; ++j) bfr.s[j] = bp[j * TPITCH];
                sa[0] = MFMA(AW[0][ks].v, bfr.v, sa[0]);
                sa[1] = MFMA(AW[1][ks].v, bfr.v, sa[1]);
            }
            float* rp = red + wv * (32 * REDP);
#pragma unroll
            for (int mh = 0; mh < 2; ++mh)
#pragma unroll
                for (int r = 0; r < 4; ++r)
                    rp[(mh * 16 + q * 4 + r) * REDP + ln] = sa[mh][r];
        }
        __syncthreads();                     // (A) partials visible

        // --- reduce 8 K-partials + bias, relu; write att_out + Sb ---
        {
            const int m  = t >> 4;
            const int pp = t & 15;
            float v = bias;
#pragma unroll
            for (int kp = 0; kp < 8; ++kp)
                v += red[kp * (32 * REDP) + m * REDP + pp];
            v = fmaxf(v, 0.f);
            const int pg = hg * 16 + pp;
            if (pg < 676) att_out[(size_t)(b * 32 + m) * 676 + pg] = v;
            // T pad cols are zero -> pad att never reaches pooled
            Sb[m * TPITCH + s * 16 + pp] = f2b(v);
        }
        __syncthreads();                     // (B) att_out/Sb visible, red free

        // --- pool every 2nd half-tile: K=32 over the paired cols ---
        if (s) {
            Frag af[2];
#pragma unroll
            for (int mh = 0; mh < 2; ++mh)
                af[mh].u4 = *(const uint32x4*)(Sb + (mh * 16 + ln) * TPITCH + q * 8);
#pragma unroll
            for (int ct = 0; ct < 6; ++ct) {
                Frag bfr;
                bfr.u4 = *(const uint32x4*)(T + (kwv + ct * 16 + ln) * TPITCH
                           + ((q ^ ((2 * ct + (ln >> 3)) & 3)) << 3));
                accp[0][ct] = MFMA(af[0].v, bfr.v, accp[0][ct]);
                accp[1][ct] = MFMA(af[1].v, bfr.v, accp[1][ct]);
            }
            __syncthreads();                 // (C) T fully consumed
        }

        if (h + 1 < nh) {
            commit(s ^ 1);                   // write the dead half-slot
            __syncthreads();                 // (D) next slot ready
        }
    }

    // epilogue: pooled partial, pre-scaled by 1/676, atomic across sp-blocks
    const float sc = 1.0f / 676.0f;
#pragma unroll
    for (int mh = 0; mh < 2; ++mh)
#pragma unroll
        for (int ct = 0; ct < 6; ++ct) {
            const int c = kwv + ct * 16 + ln;
#pragma unroll
            for (int r = 0; r < 4; ++r) {
                const int m = mh * 16 + q * 4 + r;
                atomicAdd(pooled + (size_t)(b * 32 + m) * 768 + c,
                          accp[mh][ct][r] * sc);
            }
        }
}

// ---- Pass 2: p_sums[b][ch] = sum|pooled chunk| ----  grid (64, 4)
__global__ __launch_bounds__(256) void k_psum(
    const float* __restrict__ pooled, float* __restrict__ p_sums)
{
    const int b = blockIdx.x, ch = blockIdx.y, t = threadIdx.x;
    const size_t base = (size_t)b * 24576 + (size_t)ch * 6144;
    float s = 0.f;
#pragma unroll
    for (int i = 0; i < 6; ++i) {
        f32x4_t o = *(const f32x4_t*)(pooled + base + (size_t)(i * 1024 + t * 4));
#pragma unroll
        for (int j = 0; j < 4; ++j) s += fabsf(o[j]);
    }
    __shared__ float rs[4];
    for (int off = 32; off > 0; off >>= 1) s += __shfl_down(s, off);
    if ((t & 63) == 0) rs[t >> 6] = s;
    __syncthreads();
    if (t == 0) p_sums[b * 4 + ch] = rs[0] + rs[1] + rs[2] + rs[3];
}

// ---- Pass 3: signed sqrt + L2 normalize ----
__global__ __launch_bounds__(256) void k_norm(
    const float* __restrict__ pooled, const float* __restrict__ p_sums,
    float* __restrict__ fm_out, u16* __restrict__ fmn16)
{
    const int b = blockIdx.x;
    const size_t base = (size_t)b * 24576 + (size_t)blockIdx.y * 2048;
    const float* s4 = p_sums + b * 4;
    const float tot = ((s4[0] + s4[1]) + (s4[2] + s4[3])) + 24576.f * 1e-12f;
    const float inv = 1.f / fmaxf(sqrtf(tot), 1e-12f);
    const int t = threadIdx.x;
#pragma unroll
    for (int i = 0; i < 8; ++i) {
        const size_t idx = base + i * 256 + t;
        float x = pooled[idx];
        float v = (x == 0.f) ? 0.f : copysignf(sqrtf(fabsf(x) + 1e-12f), x);
        float o = v * inv;
        fm_out[idx] = o;
        fmn16[idx]  = f2b(o);
    }
}

// ---- Pass 4: p partials, K=24576 split into 48 slabs of 512 ----
__global__ __launch_bounds__(256) void k_fc(
    const u16* __restrict__ fmn16, const float* __restrict__ fc_w,
    float* __restrict__ p_part)
{
    const int ntile = blockIdx.x;          // 0..12
    const int slab  = blockIdx.y;          // 0..47
    const int t = threadIdx.x;
    const int wv = t >> 6, l = t & 63, q = l >> 4, ln = l & 15;
    const int n = ntile * 16 + ln;
    const int kbase = slab * 512;

    const u16*   Ab = fmn16 + (size_t)(wv * 16 + ln) * 24576 + kbase + q * 8;
    const float* Bb = fc_w + (size_t)n * 24576 + kbase + q * 8;
    const bool nok = n < 200;

    f32x4_t acc = {0.f, 0.f, 0.f, 0.f};
#pragma unroll
    for (int kk = 0; kk < 512; kk += 32) {
        Frag af, bf2;
        af.u4 = *(const uint32x4*)(Ab + kk);
        if (nok) load8_cvt(Bb + kk, bf2);
        else { bf2.u[0] = 0u; bf2.u[1] = 0u; bf2.u[2] = 0u; bf2.u[3] = 0u; }
        acc = MFMA(af.v, bf2.v, acc);
    }
#pragma unroll
    for (int r = 0; r < 4; ++r) {
        const int bb = wv * 16 + q * 4 + r;
        p_part[(size_t)(slab * 64 + bb) * 208 + ntile * 16 + ln] = acc[r];
    }
}

// ---- Pass 5: reduce 48 slabs, scale 100, + bias ----
__global__ __launch_bounds__(256) void k_fin(
    const float* __restrict__ p_part, const float* __restrict__ fc_b,
    float* __restrict__ p_out)
{
    const int tid = blockIdx.x * 256 + threadIdx.x;   // 50*256 == 12800
    const int b = tid / 200, n = tid - b * 200;
    float s = 0.f;
#pragma unroll
    for (int sl = 0; sl < 48; ++sl) s += p_part[(size_t)(sl * 64 + b) * 208 + n];
    p_out[tid] = s * 100.f + fc_b[n];
}

extern "C" void kernel_launch(void* const* d_in, const int* in_sizes, int n_in,
                              void* d_out, int out_size, void* d_ws, size_t ws_size,
                              hipStream_t stream)
{
    const float* fm    = (const float*)d_in[0];
    const float* att_w = (const float*)d_in[1];
    const float* att_b = (const float*)d_in[2];
    const float* fc_w  = (const float*)d_in[3];
    const float* fc_b  = (const float*)d_in[4];

    float* out     = (float*)d_out;
    float* p_out   = out;                         // [64][200]
    float* fm_out  = out + 12800;                 // [64][32][768]
    float* att_out = out + 12800 + 64 * 32 * 768; // [64][32][676]

    char* ws = (char*)d_ws;
    const size_t POOL_B = 6291456;    // [64][32][768] f32
    const size_t FMN_B  = 3145728;    // [64][24576] bf16
    float* pooled = (float*)ws;
    u16*   fmn16  = (u16*)(ws + POOL_B);
    float* p_sums = (float*)(ws + POOL_B + FMN_B);
    float* p_part = (float*)ws;       // overlays pooled (dead by k_fc)

    static int attr_done = 0;
    if (!attr_done) {
        hipFuncSetAttribute(reinterpret_cast<const void*>(&k_fused),
            hipFuncAttributeMaxDynamicSharedMemorySize, LDS_BYTES);
        attr_done = 1;
    }

    hipMemsetAsync(pooled, 0, POOL_B, stream);
    k_fused<<<dim3(8, 64), 512, LDS_BYTES, stream>>>(
        fm, att_w, att_b, att_out, pooled);
    k_psum<<<dim3(64, 4), 256, 0, stream>>>(pooled, p_sums);
    k_norm<<<dim3(64, 12), 256, 0, stream>>>(pooled, p_sums, fm_out, fmn16);
    k_fc  <<<dim3(13, 48), 256, 0, stream>>>(fmn16, fc_w, p_part);
    k_fin <<<dim3(50),     256, 0, stream>>>(p_part, fc_b, p_out);
}

// Round 7
// 288.199 us; speedup vs baseline: 1.0265x; 1.0265x over previous
//
#include <hip/hip_runtime.h>
#include <hip/hip_bf16.h>

// WSDAN fused pipeline, R14.
// Inputs (f32): fm [64][768][676], att_w [192][768] (rows 0..31 used),
//               att_b [192], fc_w [200][24576], fc_b [200]
// d_out (f32): p [64*200] | fm_n [64*32*768] | att_m [64*32*676]
//
// R14 = R13 with the VGPR cap fixed the way that empirically works:
// __launch_bounds__(512, 2). hipcc treats the 2nd arg CUDA-style as min
// BLOCKS/CU: R11-R13's (512,4)/waves_per_eu gave a 64-VGPR cap -> ~55 regs
// spilled around every phase of the loop (R12/R13 counters: ~65 MB excess
// FETCH, MfmaUtil 1.4%, everything idle). arg=2 -> 4 waves/EU -> 128-VGPR
// budget; design needs ~118 (accp 48 + AW 24 + pre 24 + addressing).
// R8/R10 (the two healthy rounds) both used (512,2).

typedef unsigned short u16;
typedef __bf16 bf16x8_t __attribute__((ext_vector_type(8)));
typedef float f32x4_t __attribute__((ext_vector_type(4)));
typedef unsigned int uint32x4 __attribute__((ext_vector_type(4)));

union Frag { uint32x4 u4; unsigned u[4]; u16 s[8]; bf16x8_t v; };
union BFU { __hip_bfloat16 h; u16 u; };

__device__ inline u16 f2b(float x) { BFU t; t.h = __float2bfloat16(x); return t.u; }

__device__ inline void load8_cvt(const float* p, Frag& f) {
    f32x4_t x0 = *(const f32x4_t*)(p);
    f32x4_t x1 = *(const f32x4_t*)(p + 4);
#pragma unroll
    for (int j = 0; j < 4; ++j) { f.s[j] = f2b(x0[j]); f.s[4 + j] = f2b(x1[j]); }
}

#define MFMA(a, b, c) __builtin_amdgcn_mfma_f32_16x16x32_bf16((a), (b), (c), 0, 0, 0)

// LDS (dynamic, 81,408 B; 2 x 81,408 <= 163,840 -> 2 blocks/CU):
//   T  : [768][40] u16, XOR-chunk swizzled (verified R10 formula):
//        off_u16(c,p) = c*40 + ((p>>3) ^ ((c>>3)&3))*8 + (p&7)
//   red: [8][32][17] f32   per-K-slice att partials
//   Sb : [32][40] u16      relu'd att tile (pool A operand), col = s*16+pp
#define TPITCH 40
#define REDP 17
#define RED_OFF 61440                           // 768*40*2
#define SB_OFF (RED_OFF + 8 * 32 * REDP * 4)    // 78848
#define LDS_BYTES (SB_OFF + 32 * TPITCH * 2)    // 81408

// ---- Pass 1 (fused): att + pooled partial (atomic) ----
// grid (8, 64), 512 threads (8 waves), 2 blocks/CU.
// 44 half-tiles of 16 cols split {6,6,6,6,6,6,4,4} across sp.
// Per half-tile h: [issue loads h+1 -> pre regs] att (wave wv owns K-slice
// wv*96, AW in regs) -> red -> barrier -> reduce(+bias,relu) -> att_out+Sb
// -> barrier -> [odd h: pool over paired 32 cols, acc in regs -> barrier]
// -> commit h+1 (vmcnt wait; targets the dead half-slot) -> barrier.
__global__ __launch_bounds__(512, 2) void k_fused(
    const float* __restrict__ fm, const float* __restrict__ att_w,
    const float* __restrict__ att_b, float* __restrict__ att_out,
    float* __restrict__ pooled)
{
    const int sp = blockIdx.x;               // spatial eighth 0..7
    const int b  = blockIdx.y;
    const int t  = threadIdx.x;
    const int wv = t >> 6, l = t & 63, q = l >> 4, ln = l & 15;

    const int t0  = (sp < 6) ? sp * 3 : 18 + (sp - 6) * 2;  // full-tile base
    const int nh  = (sp < 6) ? 6 : 4;                       // half-tiles
    const int hg0 = t0 * 2;

    extern __shared__ char lds[];
    u16*   T   = (u16*)lds;
    float* red = (float*)(lds + RED_OFF);
    u16*   Sb  = (u16*)(lds + SB_OFF);

    // att_w A-fragments register-resident (kills the L2-evict HBM re-fetch)
    const int kwv = wv * 96;
    Frag AW[2][3];
#pragma unroll
    for (int mh = 0; mh < 2; ++mh)
#pragma unroll
        for (int ks = 0; ks < 3; ++ks)
            load8_cvt(att_w + (size_t)(mh * 16 + ln) * 768 + kwv + ks * 32 + q * 8,
                      AW[mh][ks]);

    const float bias = att_b[t >> 4];        // m owned in the reduce phase

    f32x4_t accp[2][6];                      // pooled acc: [mh][ct]
#pragma unroll
    for (int i = 0; i < 2; ++i)
#pragma unroll
        for (int j = 0; j < 6; ++j) accp[i][j] = f32x4_t{0.f, 0.f, 0.f, 0.f};

    // staging: thread covers c-rows rr+256i (i<3), 8 p-cols at (t&1)*8
    const int rr  = t >> 1;                  // 0..255
    const int ph8 = (t & 1) << 3;            // 0 or 8
    const int cw  = (rr >> 3) & 3;           // (c>>3)&3, i-invariant (256%32==0)
    const float* fb = fm + ((size_t)b * 768 + rr) * 676;
    f32x4_t pre[3][2];                       // 24 VGPR held across compute

    auto loadf = [&](int hg) {               // issue 6 f32x4 loads (in flight)
        const int c0 = hg * 16 + ph8;
        const bool ok0 = (c0 + 3) < 676;     // edge half-tiles 42/43 only
        const bool ok1 = (c0 + 7) < 676;
#pragma unroll
        for (int i = 0; i < 3; ++i) {
            const float* src = fb + (size_t)(i * 256) * 676 + c0;
            pre[i][0] = ok0 ? *(const f32x4_t*)(src)     : f32x4_t{0.f,0.f,0.f,0.f};
            pre[i][1] = ok1 ? *(const f32x4_t*)(src + 4) : f32x4_t{0.f,0.f,0.f,0.f};
        }
    };
    auto commit = [&](int s) {               // cvt + LDS write (waits vmcnt)
        const int chunk = (2 * s + (t & 1)) ^ cw;
#pragma unroll
        for (int i = 0; i < 3; ++i) {
            Frag w;
#pragma unroll
            for (int j = 0; j < 4; ++j) {
                w.s[j]     = f2b(pre[i][0][j]);
                w.s[4 + j] = f2b(pre[i][1][j]);
            }
            *(uint32x4*)(T + (rr + i * 256) * TPITCH + chunk * 8) = w.u4;
        }
    };

    loadf(hg0); commit(0); __syncthreads();

    for (int h = 0; h < nh; ++h) {
        const int hg = hg0 + h, s = h & 1;

        if (h + 1 < nh) loadf(hg + 1);       // issue early; awaited in commit

        // --- att: S_wv[32m][16p] over K-slice kwv..kwv+96, slot s ---
        // B elem (c = kwv+ks*32+q*8+j, p = s*16+ln): (c>>3)&3 == q here,
        // stored chunk = (2s + (ln>>3)) ^ q.
        {
            f32x4_t sa[2];
            sa[0] = f32x4_t{0.f,0.f,0.f,0.f};
            sa[1] = f32x4_t{0.f,0.f,0.f,0.f};
#pragma unroll
            for (int ks = 0; ks < 3; ++ks) {
                Frag bfr;
                const u16* bp = T + (kwv + ks * 32 + q * 8) * TPITCH
                              + (((2 * s + (ln >> 3)) ^ q) << 3) + (ln & 7);
#pragma unroll
                for (int j = 0; j < 8; ++j) bfr.s[j] = bp[j * TPITCH];
                sa[0] = MFMA(AW[0][ks].v, bfr.v, sa[0]);
                sa[1] = MFMA(AW[1][ks].v, bfr.v, sa[1]);
            }
            float* rp = red + wv * (32 * REDP);
#pragma unroll
            for (int mh = 0; mh < 2; ++mh)
#pragma unroll
                for (int r = 0; r < 4; ++r)
                    rp[(mh * 16 + q * 4 + r) * REDP + ln] = sa[mh][r];
        }
        __syncthreads();                     // (A) partials visible

        // --- reduce 8 K-partials + bias, relu; write att_out + Sb ---
        {
            const int m  = t >> 4;
            const int pp = t & 15;
            float v = bias;
#pragma unroll
            for (int kp = 0; kp < 8; ++kp)
                v += red[kp * (32 * REDP) + m * REDP + pp];
            v = fmaxf(v, 0.f);
            const int pg = hg * 16 + pp;
            if (pg < 676) att_out[(size_t)(b * 32 + m) * 676 + pg] = v;
            // T pad cols are zero -> pad att never reaches pooled
            Sb[m * TPITCH + s * 16 + pp] = f2b(v);
        }
        __syncthreads();                     // (B) att_out/Sb visible, red free

        // --- pool every 2nd half-tile: K=32 over the paired cols ---
        if (s) {
            Frag af[2];
#pragma unroll
            for (int mh = 0; mh < 2; ++mh)
                af[mh].u4 = *(const uint32x4*)(Sb + (mh * 16 + ln) * TPITCH + q * 8);
#pragma unroll
            for (int ct = 0; ct < 6; ++ct) {
                Frag bfr;
                bfr.u4 = *(const uint32x4*)(T + (kwv + ct * 16 + ln) * TPITCH
                           + ((q ^ ((2 * ct + (ln >> 3)) & 3)) << 3));
                accp[0][ct] = MFMA(af[0].v, bfr.v, accp[0][ct]);
                accp[1][ct] = MFMA(af[1].v, bfr.v, accp[1][ct]);
            }
            __syncthreads();                 // (C) T fully consumed
        }

        if (h + 1 < nh) {
            commit(s ^ 1);                   // write the dead half-slot
            __syncthreads();                 // (D) next slot ready
        }
    }

    // epilogue: pooled partial, pre-scaled by 1/676, atomic across sp-blocks
    const float sc = 1.0f / 676.0f;
#pragma unroll
    for (int mh = 0; mh < 2; ++mh)
#pragma unroll
        for (int ct = 0; ct < 6; ++ct) {
            const int c = kwv + ct * 16 + ln;
#pragma unroll
            for (int r = 0; r < 4; ++r) {
                const int m = mh * 16 + q * 4 + r;
                atomicAdd(pooled + (size_t)(b * 32 + m) * 768 + c,
                          accp[mh][ct][r] * sc);
            }
        }
}

// ---- Pass 2: p_sums[b][ch] = sum|pooled chunk| ----  grid (64, 4)
__global__ __launch_bounds__(256) void k_psum(
    const float* __restrict__ pooled, float* __restrict__ p_sums)
{
    const int b = blockIdx.x, ch = blockIdx.y, t = threadIdx.x;
    const size_t base = (size_t)b * 24576 + (size_t)ch * 6144;
    float s = 0.f;
#pragma unroll
    for (int i = 0; i < 6; ++i) {
        f32x4_t o = *(const f32x4_t*)(pooled + base + (size_t)(i * 1024 + t * 4));
#pragma unroll
        for (int j = 0; j < 4; ++j) s += fabsf(o[j]);
    }
    __shared__ float rs[4];
    for (int off = 32; off > 0; off >>= 1) s += __shfl_down(s, off);
    if ((t & 63) == 0) rs[t >> 6] = s;
    __syncthreads();
    if (t == 0) p_sums[b * 4 + ch] = rs[0] + rs[1] + rs[2] + rs[3];
}

// ---- Pass 3: signed sqrt + L2 normalize ----
__global__ __launch_bounds__(256) void k_norm(
    const float* __restrict__ pooled, const float* __restrict__ p_sums,
    float* __restrict__ fm_out, u16* __restrict__ fmn16)
{
    const int b = blockIdx.x;
    const size_t base = (size_t)b * 24576 + (size_t)blockIdx.y * 2048;
    const float* s4 = p_sums + b * 4;
    const float tot = ((s4[0] + s4[1]) + (s4[2] + s4[3])) + 24576.f * 1e-12f;
    const float inv = 1.f / fmaxf(sqrtf(tot), 1e-12f);
    const int t = threadIdx.x;
#pragma unroll
    for (int i = 0; i < 8; ++i) {
        const size_t idx = base + i * 256 + t;
        float x = pooled[idx];
        float v = (x == 0.f) ? 0.f : copysignf(sqrtf(fabsf(x) + 1e-12f), x);
        float o = v * inv;
        fm_out[idx] = o;
        fmn16[idx]  = f2b(o);
    }
}

// ---- Pass 4: p partials, K=24576 split into 48 slabs of 512 ----
__global__ __launch_bounds__(256) void k_fc(
    const u16* __restrict__ fmn16, const float* __restrict__ fc_w,
    float* __restrict__ p_part)
{
    const int ntile = blockIdx.x;          // 0..12
    const int slab  = blockIdx.y;          // 0..47
    const int t = threadIdx.x;
    const int wv = t >> 6, l = t & 63, q = l >> 4, ln = l & 15;
    const int n = ntile * 16 + ln;
    const int kbase = slab * 512;

    const u16*   Ab = fmn16 + (size_t)(wv * 16 + ln) * 24576 + kbase + q * 8;
    const float* Bb = fc_w + (size_t)n * 24576 + kbase + q * 8;
    const bool nok = n < 200;

    f32x4_t acc = {0.f, 0.f, 0.f, 0.f};
#pragma unroll
    for (int kk = 0; kk < 512; kk += 32) {
        Frag af, bf2;
        af.u4 = *(const uint32x4*)(Ab + kk);
        if (nok) load8_cvt(Bb + kk, bf2);
        else { bf2.u[0] = 0u; bf2.u[1] = 0u; bf2.u[2] = 0u; bf2.u[3] = 0u; }
        acc = MFMA(af.v, bf2.v, acc);
    }
#pragma unroll
    for (int r = 0; r < 4; ++r) {
        const int bb = wv * 16 + q * 4 + r;
        p_part[(size_t)(slab * 64 + bb) * 208 + ntile * 16 + ln] = acc[r];
    }
}

// ---- Pass 5: reduce 48 slabs, scale 100, + bias ----
__global__ __launch_bounds__(256) void k_fin(
    const float* __restrict__ p_part, const float* __restrict__ fc_b,
    float* __restrict__ p_out)
{
    const int tid = blockIdx.x * 256 + threadIdx.x;   // 50*256 == 12800
    const int b = tid / 200, n = tid - b * 200;
    float s = 0.f;
#pragma unroll
    for (int sl = 0; sl < 48; ++sl) s += p_part[(size_t)(sl * 64 + b) * 208 + n];
    p_out[tid] = s * 100.f + fc_b[n];
}

extern "C" void kernel_launch(void* const* d_in, const int* in_sizes, int n_in,
                              void* d_out, int out_size, void* d_ws, size_t ws_size,
                              hipStream_t stream)
{
    const float* fm    = (const float*)d_in[0];
    const float* att_w = (const float*)d_in[1];
    const float* att_b = (const float*)d_in[2];
    const float* fc_w  = (const float*)d_in[3];
    const float* fc_b  = (const float*)d_in[4];

    float* out     = (float*)d_out;
    float* p_out   = out;                         // [64][200]
    float* fm_out  = out + 12800;                 // [64][32][768]
    float* att_out = out + 12800 + 64 * 32 * 768; // [64][32][676]

    char* ws = (char*)d_ws;
    const size_t POOL_B = 6291456;    // [64][32][768] f32
    const size_t FMN_B  = 3145728;    // [64][24576] bf16
    float* pooled = (float*)ws;
    u16*   fmn16  = (u16*)(ws + POOL_B);
    float* p_sums = (float*)(ws + POOL_B + FMN_B);
    float* p_part = (float*)ws;       // overlays pooled (dead by k_fc)

    static int attr_done = 0;
    if (!attr_done) {
        hipFuncSetAttribute(reinterpret_cast<const void*>(&k_fused),
            hipFuncAttributeMaxDynamicSharedMemorySize, LDS_BYTES);
        attr_done = 1;
    }

    hipMemsetAsync(pooled, 0, POOL_B, stream);
    k_fused<<<dim3(8, 64), 512, LDS_BYTES, stream>>>(
        fm, att_w, att_b, att_out, pooled);
    k_psum<<<dim3(64, 4), 256, 0, stream>>>(pooled, p_sums);
    k_norm<<<dim3(64, 12), 256, 0, stream>>>(pooled, p_sums, fm_out, fmn16);
    k_fc  <<<dim3(13, 48), 256, 0, stream>>>(fmn16, fc_w, p_part);
    k_fin <<<dim3(50),     256, 0, stream>>>(p_part, fc_b, p_out);
}